// Round 5
// baseline (438.188 us; speedup 1.0000x reference)
//
#include <hip/hip_runtime.h>
#include <hip/hip_bf16.h>

#define T_STEPS 24
#define NB      512
#define HID     128
#define INDIM   64
#define BN      16384

typedef __bf16 bf16_t;
typedef __bf16 bf16x8 __attribute__((ext_vector_type(8)));
typedef float  f32x16 __attribute__((ext_vector_type(16)));

__device__ __forceinline__ float sigm_(float x)  { return 1.f / (1.f + __expf(-x)); }
__device__ __forceinline__ float tanh_(float x)  { float e = __expf(-2.f * x); return (1.f - e) / (1.f + e); }

// ---------------------------------------------------------------------------
// Pack kernel. Frag layout everywhere: [ct][ks][64 lanes][8 bf16], frag = 512 elems.
//  Wrz [8ct][16ks]: cols 0..255 = [r|z], K=256 = [emb(128)|h(128)]
//  Win [4ct][8ks]:  cols 0..127 = i_n rows of Wih (256..383), K=128 (emb)
//  Whn [4ct][8ks]:  cols 0..127 = h_n rows of Whh (256..383), K=128 (h)
//  WmP [4ct][4ks]:  cols 0..127 = W_mlp, K=64 (x)
//  bc  [512] f32:   [0..255]=bih+bhh (rz), [256..383]=bih_n, [384..511]=bhh_n
// ---------------------------------------------------------------------------
__global__ void pack_kernel(const float* __restrict__ Wm,
                            const float* __restrict__ Wih, const float* __restrict__ Whh,
                            const float* __restrict__ bih, const float* __restrict__ bhh,
                            bf16_t* __restrict__ Wrz, bf16_t* __restrict__ Win,
                            bf16_t* __restrict__ Whn, bf16_t* __restrict__ WmP,
                            float* __restrict__ bc)
{
    int tid = blockIdx.x * 256 + threadIdx.x;
    if (tid < 65536) {                         // Wrz
        int e = tid & 7, l = (tid >> 3) & 63, ks = (tid >> 9) & 15, ct = tid >> 13;
        int col = ct * 32 + (l & 31);          // 0..255
        int k   = ks * 16 + ((l >> 5) << 3) + e;   // 0..255
        float v = (k < 128) ? Wih[col * HID + k] : Whh[col * HID + (k - 128)];
        Wrz[tid] = (bf16_t)v;
    } else if (tid < 81920) {                  // Win
        int u = tid - 65536;
        int e = u & 7, l = (u >> 3) & 63, ks = (u >> 9) & 7, ct = u >> 12;
        int col = ct * 32 + (l & 31);
        int k   = ks * 16 + ((l >> 5) << 3) + e;
        Win[u] = (bf16_t)Wih[(256 + col) * HID + k];
    } else if (tid < 98304) {                  // Whn
        int u = tid - 81920;
        int e = u & 7, l = (u >> 3) & 63, ks = (u >> 9) & 7, ct = u >> 12;
        int col = ct * 32 + (l & 31);
        int k   = ks * 16 + ((l >> 5) << 3) + e;
        Whn[u] = (bf16_t)Whh[(256 + col) * HID + k];
    } else if (tid < 106496) {                 // WmP
        int u = tid - 98304;
        int e = u & 7, l = (u >> 3) & 63, ks = (u >> 9) & 3, ct = u >> 11;
        int col = ct * 32 + (l & 31);
        int k   = ks * 16 + ((l >> 5) << 3) + e;
        WmP[u] = (bf16_t)Wm[col * INDIM + k];
    } else if (tid < 107008) {                 // bc
        int j = tid - 106496;
        float v;
        if (j < 256)      v = bih[j] + bhh[j];
        else if (j < 384) v = bih[j];
        else              v = bhh[j - 128];
        bc[j] = v;
    }
}

// ---------------------------------------------------------------------------
// Persistent GRU: 256 blocks x 512 threads (8 waves, 2/SIMD); block owns 64
// rows for all 24 steps. Wave w: rowtile rt=w>>2 (32 rows), gate coltile
// ct=w&3 (r,z,i_n,h_n all at same ct -> lane-local gate combine). h carried
// in fp32 regs (16/lane). Win/Whn/WmP cached in LDS; Wrz streamed from L2.
// LDS = 128 KiB exactly. 2 barriers/step.
// ---------------------------------------------------------------------------
__global__ __launch_bounds__(512, 2) void gru_all(
    const float*  __restrict__ x, float* __restrict__ out,
    const bf16_t* __restrict__ Wrz, const bf16_t* __restrict__ Win,
    const bf16_t* __restrict__ Whn, const bf16_t* __restrict__ WmP,
    const float*  __restrict__ bc,  const float* __restrict__ bm)
{
    __shared__ __align__(16) char WinS[32768];   // 32 frags
    __shared__ __align__(16) char WhnS[32768];   // 32 frags
    __shared__ __align__(16) char WmPS[16384];   // 16 frags
    __shared__ __align__(16) char es  [16384];   // emb tile 64x128 bf16, swizzled
    __shared__ __align__(16) char hs0 [16384], hs1[16384];   // h tiles

    const int tid = threadIdx.x;          // 0..511
    const int l   = tid & 63;
    const int w   = tid >> 6;             // 0..7
    const int rt  = w >> 2;               // rowtile 0/1
    const int ct  = w & 3;                // gate coltile
    const int r0  = blockIdx.x * 64;
    const int b   = r0 >> 9;
    const int n0  = r0 & (NB - 1);

    // ---- load step-invariant weight caches; zero hs0 (h(0)=0)
    {
        const uint4* s; uint4* d;
        s = (const uint4*)Win; d = (uint4*)WinS;
        for (int i = tid; i < 2048; i += 512) d[i] = s[i];
        s = (const uint4*)Whn; d = (uint4*)WhnS;
        for (int i = tid; i < 2048; i += 512) d[i] = s[i];
        s = (const uint4*)WmP; d = (uint4*)WmPS;
        for (int i = tid; i < 1024; i += 512) d[i] = s[i];
        uint4 z4 = make_uint4(0, 0, 0, 0);
        for (int i = tid; i < 1024; i += 512) ((uint4*)hs0)[i] = z4;
    }

    const int lane31 = l & 31;
    const int hi     = l >> 5;            // k-half select (0/1)
    const int rA     = rt * 32 + lane31;  // A-operand row within block tile
    const int sw0    = (lane31 & 15) << 4;
    const int jh     = ct * 32 + lane31;  // output column within 128

    const float bRr = bc[jh], bRz = bc[128 + jh];
    const float bIN = bc[256 + jh], bHN = bc[384 + jh];
    const float bmv = bm[jh];

    // per-lane x base: row rA of the block, k-offset hi*8
    const float* xlane = x + ((size_t)b * T_STEPS * NB + n0 + rA) * INDIM + hi * 8;

    f32x16 h = {};                        // fp32 hidden state (rowtile rt, cols jh)

    for (int t = 0; t < T_STEPS; ++t) {
        const char* hsC = (t & 1) ? hs1 : hs0;
        char*       hsN = (t & 1) ? hs0 : hs1;
        __syncthreads();                  // bar1: hs(t) visible; es reads of t-1 done

        // ---- phase A: emb tile (rt, ct) = relu(x @ Wm^T + bm); x from global
        const float* xt = xlane + (size_t)t * NB * INDIM;
        f32x16 accA;
        #pragma unroll
        for (int q = 0; q < 16; ++q) accA[q] = bmv;
        #pragma unroll
        for (int ks = 0; ks < 4; ++ks) {
            float4 v0 = *(const float4*)(xt + ks * 16);
            float4 v1 = *(const float4*)(xt + ks * 16 + 4);
            union { bf16_t h8[8]; bf16x8 v; } pa;
            pa.h8[0] = (bf16_t)v0.x; pa.h8[1] = (bf16_t)v0.y;
            pa.h8[2] = (bf16_t)v0.z; pa.h8[3] = (bf16_t)v0.w;
            pa.h8[4] = (bf16_t)v1.x; pa.h8[5] = (bf16_t)v1.y;
            pa.h8[6] = (bf16_t)v1.z; pa.h8[7] = (bf16_t)v1.w;
            bf16x8 bfr = *(const bf16x8*)(WmPS + (ct * 4 + ks) * 1024 + l * 16);
            accA = __builtin_amdgcn_mfma_f32_32x32x16_bf16(pa.v, bfr, accA, 0, 0, 0);
        }
        #pragma unroll
        for (int q = 0; q < 16; ++q) {
            int rl  = (q & 3) + ((q >> 2) << 3) + (hi << 2);   // 0..31
            int row = rt * 32 + rl;
            *(bf16_t*)(es + row * 256 + ((jh * 2) ^ ((rl & 15) << 4))) =
                (bf16_t)fmaxf(accA[q], 0.f);
        }
        __syncthreads();                  // bar2: es ready

        // ---- phase B: r,z (K=256 over [emb|h]), i_n (emb), h_n (h)
        f32x16 ar, az, ai, ah;
        #pragma unroll
        for (int q = 0; q < 16; ++q) { ar[q] = bRr; az[q] = bRz; ai[q] = bIN; ah[q] = bHN; }
        #pragma unroll
        for (int kk = 0; kk < 8; ++kk) {
            int off = ((kk * 2 + hi) * 16) ^ sw0;
            bf16x8 aE = *(const bf16x8*)(es  + rA * 256 + off);
            bf16x8 aH = *(const bf16x8*)(hsC + rA * 256 + off);
            bf16x8 bRe = *(const bf16x8*)(Wrz + ((ct    ) * 16 + kk    ) * 512 + l * 8);
            bf16x8 bRh = *(const bf16x8*)(Wrz + ((ct    ) * 16 + 8 + kk) * 512 + l * 8);
            bf16x8 bZe = *(const bf16x8*)(Wrz + ((ct + 4) * 16 + kk    ) * 512 + l * 8);
            bf16x8 bZh = *(const bf16x8*)(Wrz + ((ct + 4) * 16 + 8 + kk) * 512 + l * 8);
            bf16x8 bI  = *(const bf16x8*)(WinS + (ct * 8 + kk) * 1024 + l * 16);
            bf16x8 bN  = *(const bf16x8*)(WhnS + (ct * 8 + kk) * 1024 + l * 16);
            ar = __builtin_amdgcn_mfma_f32_32x32x16_bf16(aE, bRe, ar, 0, 0, 0);
            ar = __builtin_amdgcn_mfma_f32_32x32x16_bf16(aH, bRh, ar, 0, 0, 0);
            az = __builtin_amdgcn_mfma_f32_32x32x16_bf16(aE, bZe, az, 0, 0, 0);
            az = __builtin_amdgcn_mfma_f32_32x32x16_bf16(aH, bZh, az, 0, 0, 0);
            ai = __builtin_amdgcn_mfma_f32_32x32x16_bf16(aE, bI,  ai, 0, 0, 0);
            ah = __builtin_amdgcn_mfma_f32_32x32x16_bf16(aH, bN,  ah, 0, 0, 0);
        }

        // ---- phase C: lane-local gates + h update; write h(t+1) bf16 to hsN
        #pragma unroll
        for (int q = 0; q < 16; ++q) {
            int rl  = (q & 3) + ((q >> 2) << 3) + (hi << 2);
            int row = rt * 32 + rl;
            float r  = sigm_(ar[q]);
            float z  = sigm_(az[q]);
            float n  = tanh_(ai[q] + r * ah[q]);
            float hv = n + z * (h[q] - n);
            h[q] = hv;
            *(bf16_t*)(hsN + row * 256 + ((jh * 2) ^ ((rl & 15) << 4))) = (bf16_t)hv;
        }
    }

    // ---- final store (fp32) straight from registers
    #pragma unroll
    for (int q = 0; q < 16; ++q) {
        int rl = (q & 3) + ((q >> 2) << 3) + (hi << 2);
        out[(size_t)(r0 + rt * 32 + rl) * HID + jh] = h[q];
    }
}

// ---------------------------------------------------------------------------
extern "C" void kernel_launch(void* const* d_in, const int* in_sizes, int n_in,
                              void* d_out, int out_size, void* d_ws, size_t ws_size,
                              hipStream_t stream)
{
    const float* x   = (const float*)d_in[0];
    const float* Wm  = (const float*)d_in[1];
    const float* bm  = (const float*)d_in[2];
    const float* Wih = (const float*)d_in[3];
    const float* Whh = (const float*)d_in[4];
    const float* bih = (const float*)d_in[5];
    const float* bhh = (const float*)d_in[6];

    char* ws = (char*)d_ws;
    bf16_t* Wrz = (bf16_t*)(ws);                 // 131072 B
    bf16_t* Win = (bf16_t*)(ws + 131072);        //  32768 B
    bf16_t* Whn = (bf16_t*)(ws + 163840);        //  32768 B
    bf16_t* WmP = (bf16_t*)(ws + 196608);        //  16384 B
    float*  bcp = (float*) (ws + 212992);        //   2048 B

    pack_kernel<<<418, 256, 0, stream>>>(Wm, Wih, Whh, bih, bhh, Wrz, Win, Whn, WmP, bcp);
    gru_all<<<256, 512, 0, stream>>>(x, (float*)d_out, Wrz, Win, Whn, WmP, bcp, bm);
}